// Round 2
// baseline (712.967 us; speedup 1.0000x reference)
//
#include <hip/hip_runtime.h>

#define BATCH 2048
#define CIN   512
#define COUT  512
#define GSZ   24
#define NORB  24
#define M_DIM (BATCH*GSZ)   // 49152
#define K_DIM (GSZ*CIN)     // 12288
#define N_DIM COUT          // 512
#define BM 192              // = 8 whole batches (192 = 8*24) -> batch-aligned tiles
#define BN 128
#define BK 64

typedef __bf16 bf16x8 __attribute__((ext_vector_type(8)));
typedef float  f32x4  __attribute__((ext_vector_type(4)));
typedef float  f32x16 __attribute__((ext_vector_type(16)));
typedef unsigned short u16;

__device__ __forceinline__ u16 f2bf(float f) {
  union { float f; unsigned u; } v; v.f = f;
  unsigned u = v.u;
  return (u16)((u + 0x7fffu + ((u >> 16) & 1u)) >> 16);  // RNE
}

// ---- pre-pass 1: x fp32 -> bf16 (coalesced both ways, 4 float4/thread) ----
__global__ void convert_x(const float* __restrict__ x, u16* __restrict__ xb, int n4) {
  const int base = blockIdx.x * 1024 + threadIdx.x;
#pragma unroll
  for (int i = 0; i < 4; ++i) {
    const int t = base + i * 256;
    if (t >= n4) return;
    const float4 v = *(const float4*)(x + (size_t)t * 4);
    ushort4 o;
    o.x = f2bf(v.x); o.y = f2bf(v.y); o.z = f2bf(v.z); o.w = f2bf(v.w);
    *(ushort4*)(xb + (size_t)t * 4) = o;
  }
}

// ---- pre-pass 2: weight (O,C,R) fp32 -> Bt[o][r*512+c] bf16 ----
#define TROW 520
__global__ void build_bt(const float* __restrict__ w, u16* __restrict__ bt) {
  __shared__ __align__(16) u16 lds[NORB * TROW];
  const int o = blockIdx.x;
  const int t = threadIdx.x;
  const float* wo = w + (size_t)o * K_DIM;
#pragma unroll
  for (int it = 0; it < 12; ++it) {
    const int idx = it * 256 + t;
    const float4 v = *(const float4*)(wo + idx * 4);
    const int k0 = idx * 4;
#pragma unroll
    for (int e = 0; e < 4; ++e) {
      const int k = k0 + e;
      const int c = k / 24;
      const int r = k - c * 24;
      lds[r * TROW + c] = f2bf(e == 0 ? v.x : e == 1 ? v.y : e == 2 ? v.z : v.w);
    }
  }
  __syncthreads();
  u16* bo = bt + (size_t)o * K_DIM;
#pragma unroll
  for (int it = 0; it < 6; ++it) {
    const int eidx = it * 256 + t;
    const int base = eidx * 8;
    const int r = base >> 9;
    const int c0 = base & 511;
    const uint4 v = *(const uint4*)(lds + r * TROW + c0);
    *(uint4*)(bo + base) = v;
  }
}

// ---- main GEMM: C[M,512] = A[M,K] * B[K,512] + bias ----
// R1 structure (group-structure A-reuse: A slab staged once per kb; B(r,kb)
// double-buffered, 2-deep prefetch; permutation applied at LDS-read address).
// R2: 16x16x32 -> 32x32x16 MFMA. Same LDS traffic (geometry-determined) but:
//   - MFMA pipe cycles -17% (2495 vs 2075 TF measured ceilings), issues halved
//   - A-read bank conflicts ~halved (32-row frag window = full 24-batch with
//     each row&7 residue exactly 3x, + 8 extras; 16-row windows skewed 1-3x)
//   - VALU ~halved: 3 jmap gathers/r (was 6); addr = pA ^ (ks<<4) single-XOR
//     (swizzle fields disjoint: row<<6 | chunk<<3, chunk = (ks*2+kb5) ^ (row&7))
__launch_bounds__(256, 2)
__global__ void gemm_gc(const u16* __restrict__ xb, const u16* __restrict__ bt,
                        const float* __restrict__ bias, const int* __restrict__ pair_orbit,
                        float* __restrict__ out) {
  __shared__ __align__(16) u16 As[BM * BK];        // 24 KB, single buffer (per kb)
  __shared__ __align__(16) u16 Bs[2 * BN * BK];    // 32 KB, double buffer (per r)
  __shared__ int jmap[GSZ * 25];                   // stride 25 (odd): conflict-free

  const int t   = threadIdx.x;
  const int gid = blockIdx.x;
  // XCD-aware: each XCD owns one 128-col B slice (3 MB -> L2-resident).
  const int xcd = gid & 7;
  const int n0  = (xcd & 3) * BN;
  const int m0  = ((gid >> 3) * 2 + (xcd >> 2)) * BM;

  // invert pair_orbit -> jmap[i][r] = j   (jmap[i*25 + r])
  for (int idx = t; idx < GSZ * NORB; idx += 256) {
    const int i = idx / 24;
    const int j = idx - i * 24;
    jmap[i * 25 + pair_orbit[idx]] = j;
  }

  // staging: thread t owns 16B chunk; row = t>>3, slot = t&7 holds source
  // chunk (t&7)^(row&7)  => read of chunk c at row r lives at slot c^(r&7).
  const int tr0 = t >> 3;
  const int kcg = ((t & 7) ^ (tr0 & 7)) * 8;
  const u16* aSrc = xb + (size_t)(m0 + tr0) * CIN + kcg;
  const u16* bSrc = bt + (size_t)(n0 + tr0) * K_DIM + kcg;
  u16* aDst = (u16*)As + t * 8;
  u16* bDst = (u16*)Bs + t * 8;

  auto stage_a = [&](int kb) {
#pragma unroll
    for (int it = 0; it < 6; ++it)
      __builtin_amdgcn_global_load_lds(
          (__attribute__((address_space(1))) void*)(aSrc + (size_t)it * 32 * CIN + kb * 64),
          (__attribute__((address_space(3))) void*)(aDst + it * 2048), 16, 0, 0);
  };
  auto stage_b = [&](int kb, int r, int soffElems) {
#pragma unroll
    for (int it = 0; it < 4; ++it)
      __builtin_amdgcn_global_load_lds(
          (__attribute__((address_space(1))) void*)(bSrc + (size_t)it * 32 * K_DIM + r * 512 + kb * 64),
          (__attribute__((address_space(3))) void*)(bDst + soffElems + it * 2048), 16, 0, 0);
  };

  // 4 waves, 2M x 2N; per-wave 96x64 = 3x2 fragments of 32x32
  const int w     = t >> 6;
  const int lane  = t & 63;
  const int l31   = lane & 31;
  const int laneK = (lane >> 5) << 3;    // k-block elem offset (bit 3)
  const int mw    = (w >> 1) * 96;
  const int nw    = (w & 1) * 64;

  int b24[3], i25[3];
#pragma unroll
  for (int f = 0; f < 3; ++f) {
    const int tr = mw + f * 32 + l31;    // tile row this lane reads for frag f
    const int b  = tr / 24;
    b24[f] = b * 24;
    i25[f] = (tr - b * 24) * 25;
  }
  // B addresses fully hoisted: nrow&7 == lane&7 (nw, nf*32 are multiples of 32)
  int pB[2];
#pragma unroll
  for (int nf = 0; nf < 2; ++nf) {
    const int nrow = nw + nf * 32 + l31;
    pB[nf] = (nrow << 6) ^ ((lane & 7) << 3) ^ laneK;
  }

  f32x16 acc[3][2];
#pragma unroll
  for (int i = 0; i < 3; ++i)
#pragma unroll
    for (int j = 0; j < 2; ++j)
      acc[i][j] = (f32x16)(0.f);

  stage_a(0);
  stage_b(0, 0, 0);
  __syncthreads();                 // jmap + A(kb=0) + B(0,0) ready
  stage_b(0, 1, 8192);             // B(t=1) in flight during first compute

  int rowC[3];                     // permuted A rows for current r
#pragma unroll
  for (int f = 0; f < 3; ++f) rowC[f] = b24[f] + jmap[i25[f]];   // r = 0

  for (int kb = 0; kb < 8; ++kb) {
    for (int r = 0; r < 24; ++r) {
      const int soff = (r & 1) * 8192;     // current B buffer (elems)

      // A base addr per frag: row<<6 | swizzled chunk<<3, XOR-decomposed
      int pA[3];
#pragma unroll
      for (int f = 0; f < 3; ++f)
        pA[f] = (rowC[f] << 6) ^ ((rowC[f] & 7) << 3) ^ laneK;

      // prefetch next-r permuted rows (hides jmap ds_read under MFMA cluster)
      int rowN[3];
      const int rn = (r == 23) ? 0 : (r + 1);
#pragma unroll
      for (int f = 0; f < 3; ++f) rowN[f] = b24[f] + jmap[i25[f] + rn];

#pragma unroll
      for (int h = 0; h < 2; ++h) {        // two k16-pairs: ks = 2h, 2h+1
        const int x0 = (2 * h) << 4;       // ks<<4
        const int x1 = (2 * h + 1) << 4;
        bf16x8 av0[3], av1[3], bv0[2], bv1[2];
#pragma unroll
        for (int nf = 0; nf < 2; ++nf) {
          bv0[nf] = *(const bf16x8*)(Bs + soff + (pB[nf] ^ x0));
          bv1[nf] = *(const bf16x8*)(Bs + soff + (pB[nf] ^ x1));
        }
#pragma unroll
        for (int f = 0; f < 3; ++f) {
          av0[f] = *(const bf16x8*)(As + (pA[f] ^ x0));
          av1[f] = *(const bf16x8*)(As + (pA[f] ^ x1));
        }
        __builtin_amdgcn_s_setprio(1);
#pragma unroll
        for (int mf = 0; mf < 3; ++mf)
#pragma unroll
          for (int nf = 0; nf < 2; ++nf)
            acc[mf][nf] = __builtin_amdgcn_mfma_f32_32x32x16_bf16(av0[mf], bv0[nf], acc[mf][nf], 0, 0, 0);
#pragma unroll
        for (int mf = 0; mf < 3; ++mf)
#pragma unroll
          for (int nf = 0; nf < 2; ++nf)
            acc[mf][nf] = __builtin_amdgcn_mfma_f32_32x32x16_bf16(av1[mf], bv1[nf], acc[mf][nf], 0, 0, 0);
        __builtin_amdgcn_s_setprio(0);
      }

#pragma unroll
      for (int f = 0; f < 3; ++f) rowC[f] = rowN[f];

      __syncthreads();   // drains vmcnt: B(t+1) landed; all waves done with Bs[soff]

      // post slot: stage B(t+2) into the buffer just consumed; A at kb boundary
      if (r < 22) {
        stage_b(kb, r + 2, soff);
      } else if (kb < 7) {
        if (r == 22) {
          stage_b(kb + 1, 0, soff);
        } else {            // r == 23: safe to overwrite As now
          stage_a(kb + 1);
          stage_b(kb + 1, 1, soff);
          __syncthreads();  // extra drain (8x total) so next compute sees A(kb+1)
        }
      }
    }
  }

  // epilogue: 32x32 C/D layout: col = lane&31, row = (reg&3) + 8*(reg>>2) + 4*(lane>>5)
#pragma unroll
  for (int nf = 0; nf < 2; ++nf) {
    const int col = n0 + nw + nf * 32 + l31;
    const float bv = bias[col];
#pragma unroll
    for (int mf = 0; mf < 3; ++mf) {
      const int rbase = m0 + mw + mf * 32 + ((lane >> 5) << 2);
#pragma unroll
      for (int reg = 0; reg < 16; ++reg) {
        const int row = rbase + (reg & 3) + 8 * (reg >> 2);
        out[(size_t)row * N_DIM + col] = acc[mf][nf][reg] + bv;
      }
    }
  }
}

extern "C" void kernel_launch(void* const* d_in, const int* in_sizes, int n_in,
                              void* d_out, int out_size, void* d_ws, size_t ws_size,
                              hipStream_t stream) {
  (void)in_sizes; (void)n_in; (void)out_size; (void)ws_size;
  const float* x    = (const float*)d_in[0];
  const float* wgt  = (const float*)d_in[1];
  const float* bias = (const float*)d_in[2];
  const int*   po   = (const int*)d_in[3];
  float* out = (float*)d_out;

  u16* xb = (u16*)d_ws;                       // 25,165,824 elems = 50.3 MB
  u16* bt = xb + (size_t)M_DIM * CIN;         // 512*12288 elems = 12.6 MB

  const int nx4 = (BATCH * GSZ * CIN) / 4;
  convert_x<<<nx4 / 1024, 256, 0, stream>>>(x, xb, nx4);
  build_bt<<<COUT, 256, 0, stream>>>(wgt, bt);

  const int grid = (M_DIM / BM) * (N_DIM / BN);  // 256*4 = 1024
  gemm_gc<<<grid, 256, 0, stream>>>(xb, bt, bias, po, out);
}

// Round 3
// 650.008 us; speedup vs baseline: 1.0969x; 1.0969x over previous
//
#include <hip/hip_runtime.h>

#define BATCH 2048
#define CIN   512
#define COUT  512
#define GSZ   24
#define NORB  24
#define M_DIM (BATCH*GSZ)   // 49152
#define K_DIM (GSZ*CIN)     // 12288
#define N_DIM COUT          // 512
#define BM 192              // = 8 whole batches (192 = 8*24) -> batch-aligned tiles
#define BN 128
#define BK 64

typedef __bf16 bf16x8 __attribute__((ext_vector_type(8)));
typedef float  f32x4  __attribute__((ext_vector_type(4)));
typedef unsigned short u16;

__device__ __forceinline__ u16 f2bf(float f) {
  union { float f; unsigned u; } v; v.f = f;
  unsigned u = v.u;
  return (u16)((u + 0x7fffu + ((u >> 16) & 1u)) >> 16);  // RNE
}

// ---- pre-pass 1: x fp32 -> bf16 (coalesced both ways, 4 float4/thread) ----
__global__ void convert_x(const float* __restrict__ x, u16* __restrict__ xb, int n4) {
  const int base = blockIdx.x * 1024 + threadIdx.x;
#pragma unroll
  for (int i = 0; i < 4; ++i) {
    const int t = base + i * 256;
    if (t >= n4) return;
    const float4 v = *(const float4*)(x + (size_t)t * 4);
    ushort4 o;
    o.x = f2bf(v.x); o.y = f2bf(v.y); o.z = f2bf(v.z); o.w = f2bf(v.w);
    *(ushort4*)(xb + (size_t)t * 4) = o;
  }
}

// ---- pre-pass 2: weight (O,C,R) fp32 -> Bt[o][r*512+c] bf16 ----
#define TROW 520
__global__ void build_bt(const float* __restrict__ w, u16* __restrict__ bt) {
  __shared__ __align__(16) u16 lds[NORB * TROW];
  const int o = blockIdx.x;
  const int t = threadIdx.x;
  const float* wo = w + (size_t)o * K_DIM;
#pragma unroll
  for (int it = 0; it < 12; ++it) {
    const int idx = it * 256 + t;
    const float4 v = *(const float4*)(wo + idx * 4);
    const int k0 = idx * 4;
#pragma unroll
    for (int e = 0; e < 4; ++e) {
      const int k = k0 + e;
      const int c = k / 24;
      const int r = k - c * 24;
      lds[r * TROW + c] = f2bf(e == 0 ? v.x : e == 1 ? v.y : e == 2 ? v.z : v.w);
    }
  }
  __syncthreads();
  u16* bo = bt + (size_t)o * K_DIM;
#pragma unroll
  for (int it = 0; it < 6; ++it) {
    const int eidx = it * 256 + t;
    const int base = eidx * 8;
    const int r = base >> 9;
    const int c0 = base & 511;
    const uint4 v = *(const uint4*)(lds + r * TROW + c0);
    *(uint4*)(bo + base) = v;
  }
}

// ---- main GEMM: C[M,512] = A[M,K] * B[K,512] + bias ----
// R1 structure (group-structure A-reuse, 16x16x32 MFMA, 6x4 frags/wave —
// R2's 32x32 fragment regressed: permuted-row reads put data-dependent j&7
// collisions inside one 16-lane LDS phase, conflicts 16.8M->96.5M. Reverted.)
// R3: counted-vmcnt pipeline (T3/T4):
//   - Bs triple-buffered (48 KB). Per iter: s_waitcnt vmcnt(4) (leaves B(t+1)
//     in flight) -> s_barrier -> issue B(t+2) -> compute. ONE barrier/iter,
//     loads span TWO compute phases, no vmcnt(0) drain in the main loop.
//   - wait-THEN-barrier ordering guarantees all waves' B(t) writes landed.
//   - write buf (t+2)%3 == (t-1)%3 = the buffer all waves finished reading
//     before this barrier (WAR-safe).
//   - kb boundary (7x): extra barrier after compute, then stage_a BEFORE
//     stage_b so the uniform vmcnt(4) also covers A at the next iter.
__launch_bounds__(256, 2)
__global__ void gemm_gc(const u16* __restrict__ xb, const u16* __restrict__ bt,
                        const float* __restrict__ bias, const int* __restrict__ pair_orbit,
                        float* __restrict__ out) {
  __shared__ __align__(16) u16 As[BM * BK];        // 24 KB, single buffer (per kb)
  __shared__ __align__(16) u16 Bs[3 * BN * BK];    // 48 KB, triple buffer (per r)
  __shared__ int jmap[GSZ * 25];                   // stride 25 (odd): conflict-free

  const int t   = threadIdx.x;
  const int gid = blockIdx.x;
  // XCD-aware: each XCD owns one 128-col B slice (3 MB -> L2-resident).
  const int xcd = gid & 7;
  const int n0  = (xcd & 3) * BN;
  const int m0  = ((gid >> 3) * 2 + (xcd >> 2)) * BM;

  // invert pair_orbit -> jmap[i][r] = j   (jmap[i*25 + r])
  for (int idx = t; idx < GSZ * NORB; idx += 256) {
    const int i = idx / 24;
    const int j = idx - i * 24;
    jmap[i * 25 + pair_orbit[idx]] = j;
  }

  // staging: thread t owns 16B chunk; row = t>>3, slot = t&7 holds source
  // chunk (t&7)^(row&7)  => read of chunk c at row r lives at slot c^(r&7).
  const int tr0 = t >> 3;
  const int kcg = ((t & 7) ^ (tr0 & 7)) * 8;
  const u16* aSrc = xb + (size_t)(m0 + tr0) * CIN + kcg;
  const u16* bSrc = bt + (size_t)(n0 + tr0) * K_DIM + kcg;
  u16* aDst = (u16*)As + t * 8;
  u16* bDst = (u16*)Bs + t * 8;

  auto stage_a = [&](int kb) {
#pragma unroll
    for (int it = 0; it < 6; ++it)
      __builtin_amdgcn_global_load_lds(
          (__attribute__((address_space(1))) void*)(aSrc + (size_t)it * 32 * CIN + kb * 64),
          (__attribute__((address_space(3))) void*)(aDst + it * 2048), 16, 0, 0);
  };
  auto stage_b = [&](int kb, int r, int soffElems) {
#pragma unroll
    for (int it = 0; it < 4; ++it)
      __builtin_amdgcn_global_load_lds(
          (__attribute__((address_space(1))) void*)(bSrc + (size_t)it * 32 * K_DIM + r * 512 + kb * 64),
          (__attribute__((address_space(3))) void*)(bDst + soffElems + it * 2048), 16, 0, 0);
  };

  // 4 waves, 2M x 2N, per-wave 96x64 output (6 x 4 fragments of 16x16)
  const int w    = t >> 6;
  const int lane = t & 63;
  const int lm   = lane & 15;
  const int q    = lane >> 4;
  const int mw   = (w >> 1) * 96;
  const int nw   = (w & 1) * 64;
  const int q8   = q << 3;

  int b24[6], i25[6];
#pragma unroll
  for (int f = 0; f < 6; ++f) {
    const int tr = mw + f * 16 + lm;   // tile row this lane reads for frag f
    const int b  = tr / 24;
    b24[f] = b * 24;
    i25[f] = (tr - b * 24) * 25;
  }
  // B addresses hoisted (B rows are NOT permuted)
  int baseB[4];
#pragma unroll
  for (int nf = 0; nf < 4; ++nf)
    baseB[nf] = (nw + lm + 16 * nf) * 64 + (q8 ^ ((lm & 7) << 3));

  f32x4 acc[6][4];
#pragma unroll
  for (int i = 0; i < 6; ++i)
#pragma unroll
    for (int j = 0; j < 4; ++j)
      acc[i][j] = (f32x4){0.f, 0.f, 0.f, 0.f};

  // prologue: A(0), B(0)->buf0 drained; B(1)->buf1 in flight (4 outstanding)
  stage_a(0);
  stage_b(0, 0, 0);
  __syncthreads();                 // full drain: jmap + A(0) + B(0) ready
  stage_b(0, 1, 8192);

  int rowC[6];                     // permuted A rows for current r
#pragma unroll
  for (int f = 0; f < 6; ++f) rowC[f] = b24[f] + jmap[i25[f]];   // r = 0

  int cur = 0, w2 = 2;             // read buf = t%3, write buf = (t+2)%3
  int r2 = 2, kb2 = 0;             // (t+2) -> (kb2, r2)
  int rr = 0, kb = 0;              // current (kb, r)

#pragma unroll 1
  for (int tt = 0; tt < 192; ++tt) {
    // B(tt) landed (own wave); barrier makes ALL waves' writes visible and
    // confirms everyone finished reading the buffer we stage into below.
    if (tt < 191) asm volatile("s_waitcnt vmcnt(4)" ::: "memory");
    else          asm volatile("s_waitcnt vmcnt(0)" ::: "memory");
    __builtin_amdgcn_s_barrier();
    __builtin_amdgcn_sched_barrier(0);

    const bool bnd = (rr == 23);
    if (!bnd && tt < 190) stage_b(kb2, r2, w2 << 13);   // B(tt+2) -> buf (tt+2)%3

    // A base addr per frag (swizzle keyed on the PERMUTED row; b24%8==0)
    int c0[6];
#pragma unroll
    for (int f = 0; f < 6; ++f)
      c0[f] = rowC[f] * 64 + (q8 ^ ((rowC[f] & 7) << 3));

    // prefetch next-r permuted rows (hides jmap ds_read under MFMA cluster)
    int rowN[6];
    const int rn = bnd ? 0 : (rr + 1);
#pragma unroll
    for (int f = 0; f < 6; ++f) rowN[f] = b24[f] + jmap[i25[f] + rn];

    const int soff = cur << 13;
#pragma unroll
    for (int h = 0; h < 2; ++h) {        // k-halves: chunk q / q+4  (^32 elems)
      const int hx = h * 32;
      bf16x8 av[6], bv[4];
#pragma unroll
      for (int nf = 0; nf < 4; ++nf)
        bv[nf] = *(const bf16x8*)(Bs + soff + (baseB[nf] ^ hx));
#pragma unroll
      for (int f = 0; f < 6; ++f)
        av[f] = *(const bf16x8*)(As + (c0[f] ^ hx));
      __builtin_amdgcn_s_setprio(1);
#pragma unroll
      for (int mf = 0; mf < 6; ++mf)
#pragma unroll
        for (int nf = 0; nf < 4; ++nf)
          acc[mf][nf] = __builtin_amdgcn_mfma_f32_16x16x32_bf16(av[mf], bv[nf], acc[mf][nf], 0, 0, 0);
      __builtin_amdgcn_s_setprio(0);
    }

#pragma unroll
    for (int f = 0; f < 6; ++f) rowC[f] = rowN[f];

    if (bnd && kb < 7) {
      // all waves done reading As for this kb; restage A then B so the
      // uniform vmcnt(4) next iter covers both (A older than B(tt+2)).
      __builtin_amdgcn_s_barrier();
      __builtin_amdgcn_sched_barrier(0);
      stage_a(kb + 1);
      stage_b(kb2, r2, w2 << 13);        // B(tt+2) (tt<=167 here, always valid)
    }

    cur = (cur == 2) ? 0 : cur + 1;
    w2  = (w2 == 2) ? 0 : w2 + 1;
    if (++r2 == 24) { r2 = 0; ++kb2; }
    if (++rr == 24) { rr = 0; ++kb; }
  }

  // epilogue: D row = q*4+e (m), col = lm (n); add bias[o=col]
#pragma unroll
  for (int nf = 0; nf < 4; ++nf) {
    const int col = n0 + nw + nf * 16 + lm;
    const float bv = bias[col];
#pragma unroll
    for (int mf = 0; mf < 6; ++mf) {
      const int mrow = m0 + mw + mf * 16 + q * 4;
#pragma unroll
      for (int e = 0; e < 4; ++e)
        out[(size_t)(mrow + e) * N_DIM + col] = acc[mf][nf][e] + bv;
    }
  }
}

extern "C" void kernel_launch(void* const* d_in, const int* in_sizes, int n_in,
                              void* d_out, int out_size, void* d_ws, size_t ws_size,
                              hipStream_t stream) {
  (void)in_sizes; (void)n_in; (void)out_size; (void)ws_size;
  const float* x    = (const float*)d_in[0];
  const float* wgt  = (const float*)d_in[1];
  const float* bias = (const float*)d_in[2];
  const int*   po   = (const int*)d_in[3];
  float* out = (float*)d_out;

  u16* xb = (u16*)d_ws;                       // 25,165,824 elems = 50.3 MB
  u16* bt = xb + (size_t)M_DIM * CIN;         // 512*12288 elems = 12.6 MB

  const int nx4 = (BATCH * GSZ * CIN) / 4;
  convert_x<<<nx4 / 1024, 256, 0, stream>>>(x, xb, nx4);
  build_bt<<<COUT, 256, 0, stream>>>(wgt, bt);

  const int grid = (M_DIM / BM) * (N_DIM / BN);  // 256*4 = 1024
  gemm_gc<<<grid, 256, 0, stream>>>(xb, bt, bias, po, out);
}